// Round 6
// baseline (885.159 us; speedup 1.0000x reference)
//
#include <hip/hip_runtime.h>

// Self-attention B=2, S=4096, D=1024, fp32 in/out.
//
// Round-6: k-major LDS tile layout (bank-conflict fix).
//   Round-5 counters: 8.39M conflict-cycles / 2.1M ds_read_b128 on the
//   scores dispatch = +4cy/read (~8-way aliasing): the row-major [128][32]
//   bf16 tile has 64B rows, so 16 fragment-read lanes alias onto 2 bank
//   groups. Fix: store tiles k-major [4 kg][128 row][8 bf16]; a fragment
//   read becomes 256B contiguous (2-way = free). global_load_lds dest stays
//   linear; only the per-lane GLOBAL source index is permuted (rule 21).
//
// Everything else identical to round 5 (QM trick + SPLIT engine):
//   * scores = (E*M)*E^T, Mt[d'][d] = sum_e Wk[d'][e]*Wq[d][e] precomputed.
//   * SPLIT GEMMs: hi/lo co-staged, 3 MFMAs {hh,hl,lh} per fragment pair.
//   * m97-style 128x128x32, global_load_lds width-16.

#define S_LEN 4096

typedef __bf16 bf16x8 __attribute__((ext_vector_type(8)));
typedef float f32x4 __attribute__((ext_vector_type(4)));

__device__ __forceinline__ unsigned short f2bf(float x) {
  unsigned u = __float_as_uint(x);
  unsigned r = u + 0x7fffu + ((u >> 16) & 1u);  // round-to-nearest-even
  return (unsigned short)(r >> 16);
}
__device__ __forceinline__ float bf2f(unsigned short h) {
  return __uint_as_float(((unsigned)h) << 16);
}

__device__ __forceinline__ void gl_lds16(const void* g, void* l) {
  __builtin_amdgcn_global_load_lds(
      (const __attribute__((address_space(1))) void*)g,
      (__attribute__((address_space(3))) void*)l, 16, 0, 0);
}

// ---------------------------------------------------------------------------
// split32: fp32 -> (hi, lo) bf16 pair, elementwise, float4-vectorized.
// grid * 256 * 4 must equal the element count.
__launch_bounds__(256)
__global__ void split32(const float* __restrict__ e,
                        unsigned short* __restrict__ Eh,
                        unsigned short* __restrict__ El) {
  int i = blockIdx.x * 256 + threadIdx.x;  // float4 index
  float4 v = reinterpret_cast<const float4*>(e)[i];
  ushort4 h, l;
  h.x = f2bf(v.x); l.x = f2bf(v.x - bf2f(h.x));
  h.y = f2bf(v.y); l.y = f2bf(v.y - bf2f(h.y));
  h.z = f2bf(v.z); l.z = f2bf(v.z - bf2f(h.z));
  h.w = f2bf(v.w); l.w = f2bf(v.w - bf2f(h.w));
  reinterpret_cast<ushort4*>(Eh)[i] = h;
  reinterpret_cast<ushort4*>(El)[i] = l;
}

// ---------------------------------------------------------------------------
// prep_wv: Wv[d][e] -> Wvt[e][d] plain bf16. 32x32 LDS transpose.
__launch_bounds__(256)
__global__ void prep_wv(const float* __restrict__ wv, unsigned short* __restrict__ Wvt) {
  __shared__ float tile[32][33];
  const int bx = blockIdx.x * 32;  // e block
  const int by = blockIdx.y * 32;  // d block
  const int tx = threadIdx.x;      // 0..31
  const int ty = threadIdx.y;      // 0..7
#pragma unroll
  for (int j = 0; j < 4; ++j)
    tile[ty + j * 8][tx] = wv[(long)(by + ty + j * 8) * 1024 + bx + tx];
  __syncthreads();
#pragma unroll
  for (int j = 0; j < 4; ++j) {
    float v = tile[tx][ty + j * 8];  // = Wv[by+tx][bx+ty+j*8]
    Wvt[(long)(bx + ty + j * 8) * 1024 + by + tx] = f2bf(v);
  }
}

// ---------------------------------------------------------------------------
// NT GEMM: C[m][n] = sum_k A[m][k]*B[n][k].  BM=BN=128, BK=32, 4 waves,
// 4x4 16x16x32 fragments per wave.  SPLIT=1: A,B are (hi,lo) pairs staged
// together, 3 MFMA products {hh,hl,lh} per fragment pair (fp32 emulation).
//
// LDS tile layout (k-major, round-6): granule slot s in [0,512) holds the
// 8 bf16 at global (row = s&127, k = kbase + (s>>7)*8). Fragment read for
// lane l (g=l>>4, r=l&15): &tile[g*1024 + row*8] -> 16 consecutive granules
// per 16-lane group (2-way bank aliasing = free).
//
// MODE 0: hi/lo bf16 pair store (Cp=hi, C2=lo)    [Mt precompute, QM proj]
// MODE 1: fp32 store of acc*scale + mask_filled^T  [scores]
// MODE 2: plain bf16 store                         [Vt projection]
// MODE 3: fp32 store                               [output PV]
template <int SPLIT, int MODE>
__launch_bounds__(256)
__global__ void gemm_bt(const unsigned short* __restrict__ Ah,
                        const unsigned short* __restrict__ Al, int lda,
                        const unsigned short* __restrict__ Bh,
                        const unsigned short* __restrict__ Bl, int ldb,
                        void* __restrict__ Cp, int ldc,
                        unsigned short* __restrict__ C2,
                        const float* __restrict__ mask, float scale, int kIters) {
  __shared__ unsigned short lAh[128 * 32];
  __shared__ unsigned short lBh[128 * 32];
  __shared__ unsigned short lAl[SPLIT ? 128 * 32 : 8];
  __shared__ unsigned short lBl[SPLIT ? 128 * 32 : 8];

  const int t = threadIdx.x;
  const int w = t >> 6;
  const int lane = t & 63;
  const int g = lane >> 4;
  const int r = lane & 15;
  const int wm = (w >> 1) * 64;
  const int wn = (w & 1) * 64;
  const long bm = (long)blockIdx.x * 128;
  const long bn = (long)blockIdx.y * 128;

  f32x4 acc[4][4];
  const f32x4 vzero = {0.f, 0.f, 0.f, 0.f};
#pragma unroll
  for (int mi = 0; mi < 4; ++mi)
#pragma unroll
    for (int ni = 0; ni < 4; ++ni) acc[mi][ni] = vzero;

  for (int kt = 0; kt < kIters; ++kt) {
    __syncthreads();
    const long kbase = (long)kt * 32;
#pragma unroll
    for (int i = 0; i < 2; ++i) {
      // slot s in [0,512): k-major granule (row = s&127, kg = s>>7)
      int s = (i * 4 + w) * 64 + lane;
      int row = s & 127;
      int kg = s >> 7;
      long goffA = (bm + row) * (long)lda + kbase + kg * 8;
      long goffB = (bn + row) * (long)ldb + kbase + kg * 8;
      int lbase = (i * 4 + w) * 512;  // wave-uniform LDS base (ushort units)
      gl_lds16(Ah + goffA, lAh + lbase);
      gl_lds16(Bh + goffB, lBh + lbase);
      if constexpr (SPLIT) {
        gl_lds16(Al + goffA, lAl + lbase);
        gl_lds16(Bl + goffB, lBl + lbase);
      }
    }
    __syncthreads();

    bf16x8 af[4], bfh[4], af2[4], bf2v[4];
#pragma unroll
    for (int mi = 0; mi < 4; ++mi) {
      int o = g * 1024 + (wm + mi * 16 + r) * 8;  // k-major fragment offset
      af[mi] = *reinterpret_cast<const bf16x8*>(&lAh[o]);
      if constexpr (SPLIT)
        af2[mi] = *reinterpret_cast<const bf16x8*>(&lAl[o]);
    }
#pragma unroll
    for (int ni = 0; ni < 4; ++ni) {
      int o = g * 1024 + (wn + ni * 16 + r) * 8;
      bfh[ni] = *reinterpret_cast<const bf16x8*>(&lBh[o]);
      if constexpr (SPLIT)
        bf2v[ni] = *reinterpret_cast<const bf16x8*>(&lBl[o]);
    }
#pragma unroll
    for (int mi = 0; mi < 4; ++mi)
#pragma unroll
      for (int ni = 0; ni < 4; ++ni) {
        acc[mi][ni] = __builtin_amdgcn_mfma_f32_16x16x32_bf16(af[mi], bfh[ni], acc[mi][ni], 0, 0, 0);
        if constexpr (SPLIT) {
          acc[mi][ni] = __builtin_amdgcn_mfma_f32_16x16x32_bf16(af[mi], bf2v[ni], acc[mi][ni], 0, 0, 0);
          acc[mi][ni] = __builtin_amdgcn_mfma_f32_16x16x32_bf16(af2[mi], bfh[ni], acc[mi][ni], 0, 0, 0);
        }
      }
  }

  // Epilogue. C/D layout: col = lane&15, row = 4*(lane>>4) + reg (m89-verified).
#pragma unroll
  for (int mi = 0; mi < 4; ++mi) {
#pragma unroll
    for (int ni = 0; ni < 4; ++ni) {
      long row0 = bm + wm + mi * 16 + g * 4;
      long col = bn + wn + ni * 16 + r;
#pragma unroll
      for (int q = 0; q < 4; ++q) {
        float v = acc[mi][ni][q];
        long row = row0 + q;
        if constexpr (MODE == 0) {
          unsigned short h = f2bf(v);
          ((unsigned short*)Cp)[row * (long)ldc + col] = h;
          C2[row * (long)ldc + col] = f2bf(v - bf2f(h));
        } else if constexpr (MODE == 1) {
          // scores[q_row][k_col]: add mask_filled.T = mask[k][q] (or -inf)
          float mv = mask[col * (long)S_LEN + row];
          v = v * scale;
          v = (mv == 0.0f) ? -__builtin_inff() : (v + mv);
          ((float*)Cp)[row * (long)ldc + col] = v;
        } else if constexpr (MODE == 2) {
          ((unsigned short*)Cp)[row * (long)ldc + col] = f2bf(v);
        } else {
          ((float*)Cp)[row * (long)ldc + col] = v;
        }
      }
    }
  }
}

// ---------------------------------------------------------------------------
// Row softmax, IN PLACE: reads 4096 fp32 of row blockIdx.x, writes 4096 bf16
// into the first half of the same row's storage (row stride stays 8192 ushorts).
__launch_bounds__(256)
__global__ void softmax_rows(float* __restrict__ Sc) {
  const long row = blockIdx.x;
  float* sr = Sc + row * (long)S_LEN;
  unsigned short* pr = (unsigned short*)sr;
  const int t = threadIdx.x;
  const int lane = t & 63, wid = t >> 6;

  float4 x[4];
  float m = -3.0e38f;
#pragma unroll
  for (int i = 0; i < 4; ++i) {
    x[i] = reinterpret_cast<const float4*>(sr)[t + i * 256];
    m = fmaxf(m, fmaxf(fmaxf(x[i].x, x[i].y), fmaxf(x[i].z, x[i].w)));
  }
#pragma unroll
  for (int o = 32; o; o >>= 1) m = fmaxf(m, __shfl_xor(m, o));
  __shared__ float redm[4];
  __shared__ float reds[4];
  if (lane == 0) redm[wid] = m;
  __syncthreads();
  m = fmaxf(fmaxf(redm[0], redm[1]), fmaxf(redm[2], redm[3]));

  float e[16];
  float s = 0.f;
#pragma unroll
  for (int i = 0; i < 4; ++i) {
    e[i * 4 + 0] = __expf(x[i].x - m);
    e[i * 4 + 1] = __expf(x[i].y - m);
    e[i * 4 + 2] = __expf(x[i].z - m);
    e[i * 4 + 3] = __expf(x[i].w - m);
    s += e[i * 4 + 0] + e[i * 4 + 1] + e[i * 4 + 2] + e[i * 4 + 3];
  }
#pragma unroll
  for (int o = 32; o; o >>= 1) s += __shfl_xor(s, o);
  if (lane == 0) reds[wid] = s;
  __syncthreads();
  s = reds[0] + reds[1] + reds[2] + reds[3];
  float inv = 1.0f / s;
#pragma unroll
  for (int i = 0; i < 4; ++i) {
    ushort4 o4;
    o4.x = f2bf(e[i * 4 + 0] * inv);
    o4.y = f2bf(e[i * 4 + 1] * inv);
    o4.z = f2bf(e[i * 4 + 2] * inv);
    o4.w = f2bf(e[i * 4 + 3] * inv);
    reinterpret_cast<ushort4*>(pr)[t + i * 256] = o4;
  }
}

// ---------------------------------------------------------------------------
extern "C" void kernel_launch(void* const* d_in, const int* in_sizes, int n_in,
                              void* d_out, int out_size, void* d_ws, size_t ws_size,
                              hipStream_t stream) {
  const float* emb  = (const float*)d_in[0];
  const float* mask = (const float*)d_in[1];
  const float* wq   = (const float*)d_in[2];
  const float* wk   = (const float*)d_in[3];
  const float* wv   = (const float*)d_in[4];
  float* out = (float*)d_out;
  char* ws = (char*)d_ws;

  // Workspace layout (bytes):
  //  0        Eh   [4096][1024] bf16   8,388,608
  //  8388608  El   [4096][1024] bf16   8,388,608
  //  16777216 QMh  [4096][1024] bf16   8,388,608  (after scores: Vt [1024][4096] aliases)
  //  25165824 QMl  [4096][1024] bf16   8,388,608
  //  33554432 MtH  [1024][1024] bf16   2,097,152  (Mt[d'][d] = sum_e Wk[d'][e] Wq[d][e])
  //  35651584 MtL  [1024][1024] bf16   2,097,152
  //  37748736 Wvt  [1024][1024] bf16   2,097,152
  //  39845888 scores [4096][4096] f32 67,108,864
  //    (start of scores region aliases: WqH 2M | WqL 2M | WkH 2M | WkL 2M,
  //     dead before the first scores write)
  //  need = 106,954,752  (round-2-proven envelope: 109,051,904)
  const size_t need = 106954752;
  if (ws_size < need) return;  // clean absmax fail instead of a fault (diagnostic)

  unsigned short* Eh  = (unsigned short*)(ws);
  unsigned short* El  = (unsigned short*)(ws + 8388608);
  unsigned short* QMh = (unsigned short*)(ws + 16777216);
  unsigned short* QMl = (unsigned short*)(ws + 25165824);
  unsigned short* Vt  = QMh;  // alias, live only after scores
  unsigned short* MtH = (unsigned short*)(ws + 33554432);
  unsigned short* MtL = (unsigned short*)(ws + 35651584);
  unsigned short* Wvt = (unsigned short*)(ws + 37748736);
  float* scores       = (float*)(ws + 39845888);
  unsigned short* WqH = (unsigned short*)(ws + 39845888);
  unsigned short* WqL = (unsigned short*)(ws + 39845888 + 2097152);
  unsigned short* WkH = (unsigned short*)(ws + 39845888 + 4194304);
  unsigned short* WkL = (unsigned short*)(ws + 39845888 + 6291456);

  // ---- once: split weights (ORIGINAL layout), transpose Wv, precompute Mt --
  split32<<<1024, 256, 0, stream>>>(wq, WqH, WqL);
  split32<<<1024, 256, 0, stream>>>(wk, WkH, WkL);
  prep_wv<<<dim3(32, 32), dim3(32, 8), 0, stream>>>(wv, Wvt);
  // Mt[d'][d] = sum_e Wk[d'][e]*Wq[d][e]: SPLIT NT-GEMM, A=Wk, B=Wq.
  gemm_bt<1, 0><<<dim3(8, 8), 256, 0, stream>>>(
      WkH, WkL, 1024, WqH, WqL, 1024, (void*)MtH, 1024, MtL, nullptr, 0.f, 32);

  for (int b = 0; b < 2; ++b) {
    const float* embb = emb + (size_t)b * 4096 * 1024;
    float* outb = out + (size_t)b * 4096 * 1024;

    // 1) split embeddings into bf16 hi/lo
    split32<<<4096, 256, 0, stream>>>(embb, Eh, El);
    // 2) QM[s][d'] = sum_d E[s][d]*Mt[d'][d]: SPLIT, A=E, B=Mt, hi/lo store
    gemm_bt<1, 0><<<dim3(32, 8), 256, 0, stream>>>(
        Eh, El, 1024, MtH, MtL, 1024, (void*)QMh, 1024, QMl, nullptr, 0.f, 32);
    // 3) scores = (QM * E^T)/32 + mask_filled^T: SPLIT, A=QM, B=E, fp32 store
    gemm_bt<1, 1><<<dim3(32, 32), 256, 0, stream>>>(
        QMh, QMl, 1024, Eh, El, 1024, (void*)scores, 4096, nullptr, mask, 0.03125f, 32);
    // 4) Vt[e][s] = sum_d Wvt[e][d]*E[s][d] (plain bf16; overwrites dead QMh)
    gemm_bt<0, 2><<<dim3(8, 32), 256, 0, stream>>>(
        Wvt, nullptr, 1024, Eh, nullptr, 1024, (void*)Vt, 4096, nullptr, nullptr, 0.f, 32);
    // 5) row softmax -> P bf16, in place over scores rows (row stride 8192 ushorts)
    softmax_rows<<<4096, 256, 0, stream>>>(scores);
    // 6) out = P @ V: plain, A=P (lda 8192 ushorts), B=Vt, fp32 store
    gemm_bt<0, 3><<<dim3(32, 8), 256, 0, stream>>>(
        (unsigned short*)scores, nullptr, 8192, Vt, nullptr, 4096,
        (void*)outb, 1024, nullptr, nullptr, 0.f, 128);
  }
}

// Round 7
// 627.174 us; speedup vs baseline: 1.4113x; 1.4113x over previous
//
#include <hip/hip_runtime.h>

// Self-attention B=2, S=4096, D=1024, fp32 in/out.
//
// Round-7: revert round-6's k-major staging (it zeroed bank conflicts but
// broke global coalescing: 64 lanes -> 64 cache lines, scores 130->194us).
// Replace with an XOR granule swizzle that keeps BOTH properties:
//   LDS slot s (row=s>>2) holds global granule ko = (s&3) ^ ((row>>1)&3).
//   - source: within a 4-lane row group ko is a permutation of {0..3} ->
//     same 64B segment read, coalescing identical to round 5.
//   - read: fragment offset row'*32 + (g ^ ((row'>>1)&3))*8 -> granule
//     column (4*row' + g^((row'>>1)&3)) mod 8 covers all 8 values per 8
//     rows -> 2-way bank aliasing (free) instead of 8-way.
//   Same involution on source and read (rule 21).
//
// Everything else identical to round 5 (631us baseline):
//   * QM trick: scores = (E*M)*E^T, Mt[d'][d] = sum_e Wk[d'][e]*Wq[d][e].
//   * SPLIT GEMMs: hi/lo co-staged, 3 MFMAs {hh,hl,lh} per fragment pair.
//   * m97-style 128x128x32, global_load_lds width-16.

#define S_LEN 4096

typedef __bf16 bf16x8 __attribute__((ext_vector_type(8)));
typedef float f32x4 __attribute__((ext_vector_type(4)));

__device__ __forceinline__ unsigned short f2bf(float x) {
  unsigned u = __float_as_uint(x);
  unsigned r = u + 0x7fffu + ((u >> 16) & 1u);  // round-to-nearest-even
  return (unsigned short)(r >> 16);
}
__device__ __forceinline__ float bf2f(unsigned short h) {
  return __uint_as_float(((unsigned)h) << 16);
}

__device__ __forceinline__ void gl_lds16(const void* g, void* l) {
  __builtin_amdgcn_global_load_lds(
      (const __attribute__((address_space(1))) void*)g,
      (__attribute__((address_space(3))) void*)l, 16, 0, 0);
}

// ---------------------------------------------------------------------------
// split32: fp32 -> (hi, lo) bf16 pair, elementwise, float4-vectorized.
// grid * 256 * 4 must equal the element count.
__launch_bounds__(256)
__global__ void split32(const float* __restrict__ e,
                        unsigned short* __restrict__ Eh,
                        unsigned short* __restrict__ El) {
  int i = blockIdx.x * 256 + threadIdx.x;  // float4 index
  float4 v = reinterpret_cast<const float4*>(e)[i];
  ushort4 h, l;
  h.x = f2bf(v.x); l.x = f2bf(v.x - bf2f(h.x));
  h.y = f2bf(v.y); l.y = f2bf(v.y - bf2f(h.y));
  h.z = f2bf(v.z); l.z = f2bf(v.z - bf2f(h.z));
  h.w = f2bf(v.w); l.w = f2bf(v.w - bf2f(h.w));
  reinterpret_cast<ushort4*>(Eh)[i] = h;
  reinterpret_cast<ushort4*>(El)[i] = l;
}

// ---------------------------------------------------------------------------
// prep_wv: Wv[d][e] -> Wvt[e][d] plain bf16. 32x32 LDS transpose.
__launch_bounds__(256)
__global__ void prep_wv(const float* __restrict__ wv, unsigned short* __restrict__ Wvt) {
  __shared__ float tile[32][33];
  const int bx = blockIdx.x * 32;  // e block
  const int by = blockIdx.y * 32;  // d block
  const int tx = threadIdx.x;      // 0..31
  const int ty = threadIdx.y;      // 0..7
#pragma unroll
  for (int j = 0; j < 4; ++j)
    tile[ty + j * 8][tx] = wv[(long)(by + ty + j * 8) * 1024 + bx + tx];
  __syncthreads();
#pragma unroll
  for (int j = 0; j < 4; ++j) {
    float v = tile[tx][ty + j * 8];  // = Wv[by+tx][bx+ty+j*8]
    Wvt[(long)(bx + ty + j * 8) * 1024 + by + tx] = f2bf(v);
  }
}

// ---------------------------------------------------------------------------
// NT GEMM: C[m][n] = sum_k A[m][k]*B[n][k].  BM=BN=128, BK=32, 4 waves,
// 4x4 16x16x32 fragments per wave.  SPLIT=1: A,B are (hi,lo) pairs staged
// together, 3 MFMA products {hh,hl,lh} per fragment pair (fp32 emulation).
//
// LDS swizzle (round-7): slot s holds granule (row=s>>2,
// ko = (s&3)^((row>>1)&3)). Fragment read offset:
// row'*32 + (g ^ ((row'>>1)&3))*8 -> 2-way bank aliasing, coalescing intact.
//
// MODE 0: hi/lo bf16 pair store (Cp=hi, C2=lo)    [Mt precompute, QM proj]
// MODE 1: fp32 store of acc*scale + mask_filled^T  [scores]
// MODE 2: plain bf16 store                         [Vt projection]
// MODE 3: fp32 store                               [output PV]
template <int SPLIT, int MODE>
__launch_bounds__(256)
__global__ void gemm_bt(const unsigned short* __restrict__ Ah,
                        const unsigned short* __restrict__ Al, int lda,
                        const unsigned short* __restrict__ Bh,
                        const unsigned short* __restrict__ Bl, int ldb,
                        void* __restrict__ Cp, int ldc,
                        unsigned short* __restrict__ C2,
                        const float* __restrict__ mask, float scale, int kIters) {
  __shared__ unsigned short lAh[128 * 32];
  __shared__ unsigned short lBh[128 * 32];
  __shared__ unsigned short lAl[SPLIT ? 128 * 32 : 8];
  __shared__ unsigned short lBl[SPLIT ? 128 * 32 : 8];

  const int t = threadIdx.x;
  const int w = t >> 6;
  const int lane = t & 63;
  const int g = lane >> 4;
  const int r = lane & 15;
  const int wm = (w >> 1) * 64;
  const int wn = (w & 1) * 64;
  const long bm = (long)blockIdx.x * 128;
  const long bn = (long)blockIdx.y * 128;

  f32x4 acc[4][4];
  const f32x4 vzero = {0.f, 0.f, 0.f, 0.f};
#pragma unroll
  for (int mi = 0; mi < 4; ++mi)
#pragma unroll
    for (int ni = 0; ni < 4; ++ni) acc[mi][ni] = vzero;

  for (int kt = 0; kt < kIters; ++kt) {
    __syncthreads();
    const long kbase = (long)kt * 32;
#pragma unroll
    for (int i = 0; i < 2; ++i) {
      // slot s in [0,512): row = s>>2, swizzled granule ko = (s&3)^((row>>1)&3)
      int s = (i * 4 + w) * 64 + lane;
      int row = s >> 2;
      int ko = (s & 3) ^ ((row >> 1) & 3);
      long goffA = (bm + row) * (long)lda + kbase + ko * 8;
      long goffB = (bn + row) * (long)ldb + kbase + ko * 8;
      int lbase = (i * 4 + w) * 512;  // wave-uniform LDS base (ushort units)
      gl_lds16(Ah + goffA, lAh + lbase);
      gl_lds16(Bh + goffB, lBh + lbase);
      if constexpr (SPLIT) {
        gl_lds16(Al + goffA, lAl + lbase);
        gl_lds16(Bl + goffB, lBl + lbase);
      }
    }
    __syncthreads();

    bf16x8 af[4], bfh[4], af2[4], bf2v[4];
#pragma unroll
    for (int mi = 0; mi < 4; ++mi) {
      int rowa = wm + mi * 16 + r;
      int o = rowa * 32 + ((g ^ ((rowa >> 1) & 3)) * 8);  // swizzled read
      af[mi] = *reinterpret_cast<const bf16x8*>(&lAh[o]);
      if constexpr (SPLIT)
        af2[mi] = *reinterpret_cast<const bf16x8*>(&lAl[o]);
    }
#pragma unroll
    for (int ni = 0; ni < 4; ++ni) {
      int rowb = wn + ni * 16 + r;
      int o = rowb * 32 + ((g ^ ((rowb >> 1) & 3)) * 8);
      bfh[ni] = *reinterpret_cast<const bf16x8*>(&lBh[o]);
      if constexpr (SPLIT)
        bf2v[ni] = *reinterpret_cast<const bf16x8*>(&lBl[o]);
    }
#pragma unroll
    for (int mi = 0; mi < 4; ++mi)
#pragma unroll
      for (int ni = 0; ni < 4; ++ni) {
        acc[mi][ni] = __builtin_amdgcn_mfma_f32_16x16x32_bf16(af[mi], bfh[ni], acc[mi][ni], 0, 0, 0);
        if constexpr (SPLIT) {
          acc[mi][ni] = __builtin_amdgcn_mfma_f32_16x16x32_bf16(af[mi], bf2v[ni], acc[mi][ni], 0, 0, 0);
          acc[mi][ni] = __builtin_amdgcn_mfma_f32_16x16x32_bf16(af2[mi], bfh[ni], acc[mi][ni], 0, 0, 0);
        }
      }
  }

  // Epilogue. C/D layout: col = lane&15, row = 4*(lane>>4) + reg (m89-verified).
#pragma unroll
  for (int mi = 0; mi < 4; ++mi) {
#pragma unroll
    for (int ni = 0; ni < 4; ++ni) {
      long row0 = bm + wm + mi * 16 + g * 4;
      long col = bn + wn + ni * 16 + r;
#pragma unroll
      for (int q = 0; q < 4; ++q) {
        float v = acc[mi][ni][q];
        long row = row0 + q;
        if constexpr (MODE == 0) {
          unsigned short h = f2bf(v);
          ((unsigned short*)Cp)[row * (long)ldc + col] = h;
          C2[row * (long)ldc + col] = f2bf(v - bf2f(h));
        } else if constexpr (MODE == 1) {
          // scores[q_row][k_col]: add mask_filled.T = mask[k][q] (or -inf)
          float mv = mask[col * (long)S_LEN + row];
          v = v * scale;
          v = (mv == 0.0f) ? -__builtin_inff() : (v + mv);
          ((float*)Cp)[row * (long)ldc + col] = v;
        } else if constexpr (MODE == 2) {
          ((unsigned short*)Cp)[row * (long)ldc + col] = f2bf(v);
        } else {
          ((float*)Cp)[row * (long)ldc + col] = v;
        }
      }
    }
  }
}

// ---------------------------------------------------------------------------
// Row softmax, IN PLACE: reads 4096 fp32 of row blockIdx.x, writes 4096 bf16
// into the first half of the same row's storage (row stride stays 8192 ushorts).
__launch_bounds__(256)
__global__ void softmax_rows(float* __restrict__ Sc) {
  const long row = blockIdx.x;
  float* sr = Sc + row * (long)S_LEN;
  unsigned short* pr = (unsigned short*)sr;
  const int t = threadIdx.x;
  const int lane = t & 63, wid = t >> 6;

  float4 x[4];
  float m = -3.0e38f;
#pragma unroll
  for (int i = 0; i < 4; ++i) {
    x[i] = reinterpret_cast<const float4*>(sr)[t + i * 256];
    m = fmaxf(m, fmaxf(fmaxf(x[i].x, x[i].y), fmaxf(x[i].z, x[i].w)));
  }
#pragma unroll
  for (int o = 32; o; o >>= 1) m = fmaxf(m, __shfl_xor(m, o));
  __shared__ float redm[4];
  __shared__ float reds[4];
  if (lane == 0) redm[wid] = m;
  __syncthreads();
  m = fmaxf(fmaxf(redm[0], redm[1]), fmaxf(redm[2], redm[3]));

  float e[16];
  float s = 0.f;
#pragma unroll
  for (int i = 0; i < 4; ++i) {
    e[i * 4 + 0] = __expf(x[i].x - m);
    e[i * 4 + 1] = __expf(x[i].y - m);
    e[i * 4 + 2] = __expf(x[i].z - m);
    e[i * 4 + 3] = __expf(x[i].w - m);
    s += e[i * 4 + 0] + e[i * 4 + 1] + e[i * 4 + 2] + e[i * 4 + 3];
  }
#pragma unroll
  for (int o = 32; o; o >>= 1) s += __shfl_xor(s, o);
  if (lane == 0) reds[wid] = s;
  __syncthreads();
  s = reds[0] + reds[1] + reds[2] + reds[3];
  float inv = 1.0f / s;
#pragma unroll
  for (int i = 0; i < 4; ++i) {
    ushort4 o4;
    o4.x = f2bf(e[i * 4 + 0] * inv);
    o4.y = f2bf(e[i * 4 + 1] * inv);
    o4.z = f2bf(e[i * 4 + 2] * inv);
    o4.w = f2bf(e[i * 4 + 3] * inv);
    reinterpret_cast<ushort4*>(pr)[t + i * 256] = o4;
  }
}

// ---------------------------------------------------------------------------
extern "C" void kernel_launch(void* const* d_in, const int* in_sizes, int n_in,
                              void* d_out, int out_size, void* d_ws, size_t ws_size,
                              hipStream_t stream) {
  const float* emb  = (const float*)d_in[0];
  const float* mask = (const float*)d_in[1];
  const float* wq   = (const float*)d_in[2];
  const float* wk   = (const float*)d_in[3];
  const float* wv   = (const float*)d_in[4];
  float* out = (float*)d_out;
  char* ws = (char*)d_ws;

  // Workspace layout (bytes):
  //  0        Eh   [4096][1024] bf16   8,388,608
  //  8388608  El   [4096][1024] bf16   8,388,608
  //  16777216 QMh  [4096][1024] bf16   8,388,608  (after scores: Vt [1024][4096] aliases)
  //  25165824 QMl  [4096][1024] bf16   8,388,608
  //  33554432 MtH  [1024][1024] bf16   2,097,152  (Mt[d'][d] = sum_e Wk[d'][e] Wq[d][e])
  //  35651584 MtL  [1024][1024] bf16   2,097,152
  //  37748736 Wvt  [1024][1024] bf16   2,097,152
  //  39845888 scores [4096][4096] f32 67,108,864
  //    (start of scores region aliases: WqH 2M | WqL 2M | WkH 2M | WkL 2M,
  //     dead before the first scores write)
  //  need = 106,954,752  (round-2-proven envelope: 109,051,904)
  const size_t need = 106954752;
  if (ws_size < need) return;  // clean absmax fail instead of a fault (diagnostic)

  unsigned short* Eh  = (unsigned short*)(ws);
  unsigned short* El  = (unsigned short*)(ws + 8388608);
  unsigned short* QMh = (unsigned short*)(ws + 16777216);
  unsigned short* QMl = (unsigned short*)(ws + 25165824);
  unsigned short* Vt  = QMh;  // alias, live only after scores
  unsigned short* MtH = (unsigned short*)(ws + 33554432);
  unsigned short* MtL = (unsigned short*)(ws + 35651584);
  unsigned short* Wvt = (unsigned short*)(ws + 37748736);
  float* scores       = (float*)(ws + 39845888);
  unsigned short* WqH = (unsigned short*)(ws + 39845888);
  unsigned short* WqL = (unsigned short*)(ws + 39845888 + 2097152);
  unsigned short* WkH = (unsigned short*)(ws + 39845888 + 4194304);
  unsigned short* WkL = (unsigned short*)(ws + 39845888 + 6291456);

  // ---- once: split weights (ORIGINAL layout), transpose Wv, precompute Mt --
  split32<<<1024, 256, 0, stream>>>(wq, WqH, WqL);
  split32<<<1024, 256, 0, stream>>>(wk, WkH, WkL);
  prep_wv<<<dim3(32, 32), dim3(32, 8), 0, stream>>>(wv, Wvt);
  // Mt[d'][d] = sum_e Wk[d'][e]*Wq[d][e]: SPLIT NT-GEMM, A=Wk, B=Wq.
  gemm_bt<1, 0><<<dim3(8, 8), 256, 0, stream>>>(
      WkH, WkL, 1024, WqH, WqL, 1024, (void*)MtH, 1024, MtL, nullptr, 0.f, 32);

  for (int b = 0; b < 2; ++b) {
    const float* embb = emb + (size_t)b * 4096 * 1024;
    float* outb = out + (size_t)b * 4096 * 1024;

    // 1) split embeddings into bf16 hi/lo
    split32<<<4096, 256, 0, stream>>>(embb, Eh, El);
    // 2) QM[s][d'] = sum_d E[s][d]*Mt[d'][d]: SPLIT, A=E, B=Mt, hi/lo store
    gemm_bt<1, 0><<<dim3(32, 8), 256, 0, stream>>>(
        Eh, El, 1024, MtH, MtL, 1024, (void*)QMh, 1024, QMl, nullptr, 0.f, 32);
    // 3) scores = (QM * E^T)/32 + mask_filled^T: SPLIT, A=QM, B=E, fp32 store
    gemm_bt<1, 1><<<dim3(32, 32), 256, 0, stream>>>(
        QMh, QMl, 1024, Eh, El, 1024, (void*)scores, 4096, nullptr, mask, 0.03125f, 32);
    // 4) Vt[e][s] = sum_d Wvt[e][d]*E[s][d] (plain bf16; overwrites dead QMh)
    gemm_bt<0, 2><<<dim3(8, 32), 256, 0, stream>>>(
        Wvt, nullptr, 1024, Eh, nullptr, 1024, (void*)Vt, 4096, nullptr, nullptr, 0.f, 32);
    // 5) row softmax -> P bf16, in place over scores rows (row stride 8192 ushorts)
    softmax_rows<<<4096, 256, 0, stream>>>(scores);
    // 6) out = P @ V: plain, A=P (lda 8192 ushorts), B=Vt, fp32 store
    gemm_bt<0, 3><<<dim3(32, 8), 256, 0, stream>>>(
        (unsigned short*)scores, nullptr, 8192, Vt, nullptr, 4096,
        (void*)outb, 1024, nullptr, nullptr, 0.f, 128);
  }
}

// Round 8
// 601.912 us; speedup vs baseline: 1.4706x; 1.0420x over previous
//
#include <hip/hip_runtime.h>

// Self-attention B=2, S=4096, D=1024, fp32 in/out.
//
// Round-8: deep-pipelined 8-wave 256^2 SPLIT kernel (T3-class) for the
// SCORES GEMM only. Round 7 proved the T2 regime gate on our kernel:
// XOR swizzle zeroed bank conflicts but was timing-null at the 2-barrier
// structure. This round supplies the structure:
//   BM=BN=256, BK=32, 8 waves (2Mx4N), wave tile 128x64, LDS 128KB
//   (Ah,Al,Bh,Bl x 2 dbuf x 16KB). Per K-step: 4 phases, each
//   {ds_read frags | issue gl_lds for kt+1 (front-loaded ph0/ph1) |
//    s_barrier | setprio(1) 24xMFMA setprio(0) | s_barrier}; K-step ends
//   with vmcnt(0)+__syncthreads (own-loads drained before barrier =>
//   next buffer provably complete for all waves).
// QM/Vt/PV/Mt/softmax stay on the round-7-proven 128^2 engine.
//
// Algebra unchanged: QM trick (scores = (E*M)*E^T, Mt = Wq*Wk^T from
// original-layout weights), split-bf16 {hh,hl,lh} fp32 emulation.

#define S_LEN 4096

typedef __bf16 bf16x8 __attribute__((ext_vector_type(8)));
typedef float f32x4 __attribute__((ext_vector_type(4)));

__device__ __forceinline__ unsigned short f2bf(float x) {
  unsigned u = __float_as_uint(x);
  unsigned r = u + 0x7fffu + ((u >> 16) & 1u);  // round-to-nearest-even
  return (unsigned short)(r >> 16);
}
__device__ __forceinline__ float bf2f(unsigned short h) {
  return __uint_as_float(((unsigned)h) << 16);
}

__device__ __forceinline__ void gl_lds16(const void* g, void* l) {
  __builtin_amdgcn_global_load_lds(
      (const __attribute__((address_space(1))) void*)g,
      (__attribute__((address_space(3))) void*)l, 16, 0, 0);
}

// ---------------------------------------------------------------------------
// split32: fp32 -> (hi, lo) bf16 pair, elementwise, float4-vectorized.
__launch_bounds__(256)
__global__ void split32(const float* __restrict__ e,
                        unsigned short* __restrict__ Eh,
                        unsigned short* __restrict__ El) {
  int i = blockIdx.x * 256 + threadIdx.x;  // float4 index
  float4 v = reinterpret_cast<const float4*>(e)[i];
  ushort4 h, l;
  h.x = f2bf(v.x); l.x = f2bf(v.x - bf2f(h.x));
  h.y = f2bf(v.y); l.y = f2bf(v.y - bf2f(h.y));
  h.z = f2bf(v.z); l.z = f2bf(v.z - bf2f(h.z));
  h.w = f2bf(v.w); l.w = f2bf(v.w - bf2f(h.w));
  reinterpret_cast<ushort4*>(Eh)[i] = h;
  reinterpret_cast<ushort4*>(El)[i] = l;
}

// ---------------------------------------------------------------------------
// prep_wv: Wv[d][e] -> Wvt[e][d] plain bf16. 32x32 LDS transpose.
__launch_bounds__(256)
__global__ void prep_wv(const float* __restrict__ wv, unsigned short* __restrict__ Wvt) {
  __shared__ float tile[32][33];
  const int bx = blockIdx.x * 32;
  const int by = blockIdx.y * 32;
  const int tx = threadIdx.x;
  const int ty = threadIdx.y;
#pragma unroll
  for (int j = 0; j < 4; ++j)
    tile[ty + j * 8][tx] = wv[(long)(by + ty + j * 8) * 1024 + bx + tx];
  __syncthreads();
#pragma unroll
  for (int j = 0; j < 4; ++j) {
    float v = tile[tx][ty + j * 8];
    Wvt[(long)(bx + ty + j * 8) * 1024 + by + tx] = f2bf(v);
  }
}

// ---------------------------------------------------------------------------
// Round-7 128^2 engine (proven): NT GEMM with XOR-swizzled LDS.
// MODE 0: hi/lo pair store  MODE 1: scores  MODE 2: bf16 store  MODE 3: f32.
template <int SPLIT, int MODE>
__launch_bounds__(256)
__global__ void gemm_bt(const unsigned short* __restrict__ Ah,
                        const unsigned short* __restrict__ Al, int lda,
                        const unsigned short* __restrict__ Bh,
                        const unsigned short* __restrict__ Bl, int ldb,
                        void* __restrict__ Cp, int ldc,
                        unsigned short* __restrict__ C2,
                        const float* __restrict__ mask, float scale, int kIters) {
  __shared__ unsigned short lAh[128 * 32];
  __shared__ unsigned short lBh[128 * 32];
  __shared__ unsigned short lAl[SPLIT ? 128 * 32 : 8];
  __shared__ unsigned short lBl[SPLIT ? 128 * 32 : 8];

  const int t = threadIdx.x;
  const int w = t >> 6;
  const int lane = t & 63;
  const int g = lane >> 4;
  const int r = lane & 15;
  const int wm = (w >> 1) * 64;
  const int wn = (w & 1) * 64;
  const long bm = (long)blockIdx.x * 128;
  const long bn = (long)blockIdx.y * 128;

  f32x4 acc[4][4];
  const f32x4 vzero = {0.f, 0.f, 0.f, 0.f};
#pragma unroll
  for (int mi = 0; mi < 4; ++mi)
#pragma unroll
    for (int ni = 0; ni < 4; ++ni) acc[mi][ni] = vzero;

  for (int kt = 0; kt < kIters; ++kt) {
    __syncthreads();
    const long kbase = (long)kt * 32;
#pragma unroll
    for (int i = 0; i < 2; ++i) {
      int s = (i * 4 + w) * 64 + lane;
      int row = s >> 2;
      int ko = (s & 3) ^ ((row >> 1) & 3);
      long goffA = (bm + row) * (long)lda + kbase + ko * 8;
      long goffB = (bn + row) * (long)ldb + kbase + ko * 8;
      int lbase = (i * 4 + w) * 512;
      gl_lds16(Ah + goffA, lAh + lbase);
      gl_lds16(Bh + goffB, lBh + lbase);
      if constexpr (SPLIT) {
        gl_lds16(Al + goffA, lAl + lbase);
        gl_lds16(Bl + goffB, lBl + lbase);
      }
    }
    __syncthreads();

    bf16x8 af[4], bfh[4], af2[4], bf2v[4];
#pragma unroll
    for (int mi = 0; mi < 4; ++mi) {
      int rowa = wm + mi * 16 + r;
      int o = rowa * 32 + ((g ^ ((rowa >> 1) & 3)) * 8);
      af[mi] = *reinterpret_cast<const bf16x8*>(&lAh[o]);
      if constexpr (SPLIT)
        af2[mi] = *reinterpret_cast<const bf16x8*>(&lAl[o]);
    }
#pragma unroll
    for (int ni = 0; ni < 4; ++ni) {
      int rowb = wn + ni * 16 + r;
      int o = rowb * 32 + ((g ^ ((rowb >> 1) & 3)) * 8);
      bfh[ni] = *reinterpret_cast<const bf16x8*>(&lBh[o]);
      if constexpr (SPLIT)
        bf2v[ni] = *reinterpret_cast<const bf16x8*>(&lBl[o]);
    }
#pragma unroll
    for (int mi = 0; mi < 4; ++mi)
#pragma unroll
      for (int ni = 0; ni < 4; ++ni) {
        acc[mi][ni] = __builtin_amdgcn_mfma_f32_16x16x32_bf16(af[mi], bfh[ni], acc[mi][ni], 0, 0, 0);
        if constexpr (SPLIT) {
          acc[mi][ni] = __builtin_amdgcn_mfma_f32_16x16x32_bf16(af[mi], bf2v[ni], acc[mi][ni], 0, 0, 0);
          acc[mi][ni] = __builtin_amdgcn_mfma_f32_16x16x32_bf16(af2[mi], bfh[ni], acc[mi][ni], 0, 0, 0);
        }
      }
  }

#pragma unroll
  for (int mi = 0; mi < 4; ++mi) {
#pragma unroll
    for (int ni = 0; ni < 4; ++ni) {
      long row0 = bm + wm + mi * 16 + g * 4;
      long col = bn + wn + ni * 16 + r;
#pragma unroll
      for (int q = 0; q < 4; ++q) {
        float v = acc[mi][ni][q];
        long row = row0 + q;
        if constexpr (MODE == 0) {
          unsigned short h = f2bf(v);
          ((unsigned short*)Cp)[row * (long)ldc + col] = h;
          C2[row * (long)ldc + col] = f2bf(v - bf2f(h));
        } else if constexpr (MODE == 1) {
          float mv = mask[col * (long)S_LEN + row];
          v = v * scale;
          v = (mv == 0.0f) ? -__builtin_inff() : (v + mv);
          ((float*)Cp)[row * (long)ldc + col] = v;
        } else if constexpr (MODE == 2) {
          ((unsigned short*)Cp)[row * (long)ldc + col] = f2bf(v);
        } else {
          ((float*)Cp)[row * (long)ldc + col] = v;
        }
      }
    }
  }
}

// ---------------------------------------------------------------------------
// Round-8: 256^2 8-wave deep-pipelined SPLIT NT GEMM, scores epilogue.
// C[m][n] = (sum_k A[m][k]*B[n][k]) * scale + mask_filled^T, fp32 store.
__launch_bounds__(512, 2)
__global__ void gemm8s(const unsigned short* __restrict__ Ah,
                       const unsigned short* __restrict__ Al, int lda,
                       const unsigned short* __restrict__ Bh,
                       const unsigned short* __restrict__ Bl, int ldb,
                       float* __restrict__ C, int ldc,
                       const float* __restrict__ mask, float scale, int nkt) {
  // LDS: [tile: 0=Ah 1=Al 2=Bh 3=Bl][dbuf][256 rows x 32 k], 128 KiB total.
  __shared__ __align__(16) unsigned short lds[4][2][8192];

  const int t = threadIdx.x;          // 0..511
  const int w = t >> 6;               // wave 0..7
  const int lane = t & 63;
  const int g = lane >> 4;            // 0..3
  const int r = lane & 15;
  const int wr = w >> 2;              // 0..1  (M)
  const int wc = w & 3;               // 0..3  (N)
  const long bm = (long)blockIdx.x * 256;
  const long bn = (long)blockIdx.y * 256;

  // Staging map (XOR swizzle, same involution as round 7):
  // granule slot s = chunk*512 + t; row = s>>2 = chunk*128 + (t>>2);
  // ko = (t&3) ^ ((t>>3)&3)  (chunk-invariant).
  const int row0 = t >> 2;
  const int ko = (t & 3) ^ ((t >> 3) & 3);
  const unsigned short* pAh = Ah + (bm + row0) * (long)lda + ko * 8;
  const unsigned short* pAl = Al + (bm + row0) * (long)lda + ko * 8;
  const unsigned short* pBh = Bh + (bn + row0) * (long)ldb + ko * 8;
  const unsigned short* pBl = Bl + (bn + row0) * (long)ldb + ko * 8;

  f32x4 acc[8][4];
  const f32x4 vzero = {0.f, 0.f, 0.f, 0.f};
#pragma unroll
  for (int mi = 0; mi < 8; ++mi)
#pragma unroll
    for (int ni = 0; ni < 4; ++ni) acc[mi][ni] = vzero;

  // Prologue: stage K-step 0 into buf 0 (all four tiles, both chunks).
#pragma unroll
  for (int T = 0; T < 4; ++T) {
    const unsigned short* sp = (T == 0) ? pAh : (T == 1) ? pAl : (T == 2) ? pBh : pBl;
    long ld = (T < 2) ? lda : ldb;
    gl_lds16(sp, &lds[T][0][w * 512]);
    gl_lds16(sp + 128 * ld, &lds[T][0][4096 + w * 512]);
  }
  asm volatile("s_waitcnt vmcnt(0)" ::: "memory");
  __syncthreads();

  for (int kt = 0; kt < nkt; ++kt) {
    const int cb = kt & 1, nb = cb ^ 1;
    const bool stg = (kt < nkt - 1);
    bf16x8 bh[4], bl[4];
#pragma unroll
    for (int p = 0; p < 4; ++p) {
      // --- ds_read fragments for this phase (buf cb) ---
      if (p == 0) {
#pragma unroll
        for (int ni = 0; ni < 4; ++ni) {
          int rowb = wc * 64 + ni * 16 + r;
          int o = rowb * 32 + ((g ^ ((rowb >> 1) & 3)) * 8);
          bh[ni] = *reinterpret_cast<const bf16x8*>(&lds[2][cb][o]);
          bl[ni] = *reinterpret_cast<const bf16x8*>(&lds[3][cb][o]);
        }
      }
      bf16x8 ah[2], al[2];
#pragma unroll
      for (int i = 0; i < 2; ++i) {
        int rowa = wr * 128 + (2 * p + i) * 16 + r;
        int o = rowa * 32 + ((g ^ ((rowa >> 1) & 3)) * 8);
        ah[i] = *reinterpret_cast<const bf16x8*>(&lds[0][cb][o]);
        al[i] = *reinterpret_cast<const bf16x8*>(&lds[1][cb][o]);
      }
      // --- stage next K-step (front-loaded: ph0 = A tiles, ph1 = B tiles) ---
      if (stg && p == 0) {
        gl_lds16(pAh + 32, &lds[0][nb][w * 512]);
        gl_lds16(pAh + 32 + 128 * (long)lda, &lds[0][nb][4096 + w * 512]);
        gl_lds16(pAl + 32, &lds[1][nb][w * 512]);
        gl_lds16(pAl + 32 + 128 * (long)lda, &lds[1][nb][4096 + w * 512]);
      }
      if (stg && p == 1) {
        gl_lds16(pBh + 32, &lds[2][nb][w * 512]);
        gl_lds16(pBh + 32 + 128 * (long)ldb, &lds[2][nb][4096 + w * 512]);
        gl_lds16(pBl + 32, &lds[3][nb][w * 512]);
        gl_lds16(pBl + 32 + 128 * (long)ldb, &lds[3][nb][4096 + w * 512]);
      }
      // --- phase MFMA cluster ---
      __builtin_amdgcn_s_barrier();
      __builtin_amdgcn_s_setprio(1);
#pragma unroll
      for (int i = 0; i < 2; ++i) {
        const int mi = 2 * p + i;
#pragma unroll
        for (int ni = 0; ni < 4; ++ni) {
          acc[mi][ni] = __builtin_amdgcn_mfma_f32_16x16x32_bf16(ah[i], bh[ni], acc[mi][ni], 0, 0, 0);
          acc[mi][ni] = __builtin_amdgcn_mfma_f32_16x16x32_bf16(ah[i], bl[ni], acc[mi][ni], 0, 0, 0);
          acc[mi][ni] = __builtin_amdgcn_mfma_f32_16x16x32_bf16(al[i], bh[ni], acc[mi][ni], 0, 0, 0);
        }
      }
      __builtin_amdgcn_s_setprio(0);
      if (p < 3) __builtin_amdgcn_s_barrier();
    }
    // K-step end: drain own staging loads, then full barrier -> buf swap safe.
    asm volatile("s_waitcnt vmcnt(0)" ::: "memory");
    __syncthreads();
    pAh += 32; pAl += 32; pBh += 32; pBl += 32;
  }

  // Epilogue: scores = acc*scale + mask_filled^T (mask[k][q] form).
#pragma unroll
  for (int mi = 0; mi < 8; ++mi) {
#pragma unroll
    for (int ni = 0; ni < 4; ++ni) {
      long row0q = bm + wr * 128 + mi * 16 + g * 4;
      long col = bn + wc * 64 + ni * 16 + r;
#pragma unroll
      for (int q = 0; q < 4; ++q) {
        long row = row0q + q;
        float mv = mask[col * (long)S_LEN + row];
        float v = acc[mi][ni][q] * scale;
        v = (mv == 0.0f) ? -__builtin_inff() : (v + mv);
        C[row * (long)ldc + col] = v;
      }
    }
  }
}

// ---------------------------------------------------------------------------
// Row softmax, IN PLACE: fp32 row -> bf16 P in the same storage.
__launch_bounds__(256)
__global__ void softmax_rows(float* __restrict__ Sc) {
  const long row = blockIdx.x;
  float* sr = Sc + row * (long)S_LEN;
  unsigned short* pr = (unsigned short*)sr;
  const int t = threadIdx.x;
  const int lane = t & 63, wid = t >> 6;

  float4 x[4];
  float m = -3.0e38f;
#pragma unroll
  for (int i = 0; i < 4; ++i) {
    x[i] = reinterpret_cast<const float4*>(sr)[t + i * 256];
    m = fmaxf(m, fmaxf(fmaxf(x[i].x, x[i].y), fmaxf(x[i].z, x[i].w)));
  }
#pragma unroll
  for (int o = 32; o; o >>= 1) m = fmaxf(m, __shfl_xor(m, o));
  __shared__ float redm[4];
  __shared__ float reds[4];
  if (lane == 0) redm[wid] = m;
  __syncthreads();
  m = fmaxf(fmaxf(redm[0], redm[1]), fmaxf(redm[2], redm[3]));

  float e[16];
  float s = 0.f;
#pragma unroll
  for (int i = 0; i < 4; ++i) {
    e[i * 4 + 0] = __expf(x[i].x - m);
    e[i * 4 + 1] = __expf(x[i].y - m);
    e[i * 4 + 2] = __expf(x[i].z - m);
    e[i * 4 + 3] = __expf(x[i].w - m);
    s += e[i * 4 + 0] + e[i * 4 + 1] + e[i * 4 + 2] + e[i * 4 + 3];
  }
#pragma unroll
  for (int o = 32; o; o >>= 1) s += __shfl_xor(s, o);
  if (lane == 0) reds[wid] = s;
  __syncthreads();
  s = reds[0] + reds[1] + reds[2] + reds[3];
  float inv = 1.0f / s;
#pragma unroll
  for (int i = 0; i < 4; ++i) {
    ushort4 o4;
    o4.x = f2bf(e[i * 4 + 0] * inv);
    o4.y = f2bf(e[i * 4 + 1] * inv);
    o4.z = f2bf(e[i * 4 + 2] * inv);
    o4.w = f2bf(e[i * 4 + 3] * inv);
    reinterpret_cast<ushort4*>(pr)[t + i * 256] = o4;
  }
}

// ---------------------------------------------------------------------------
extern "C" void kernel_launch(void* const* d_in, const int* in_sizes, int n_in,
                              void* d_out, int out_size, void* d_ws, size_t ws_size,
                              hipStream_t stream) {
  const float* emb  = (const float*)d_in[0];
  const float* mask = (const float*)d_in[1];
  const float* wq   = (const float*)d_in[2];
  const float* wk   = (const float*)d_in[3];
  const float* wv   = (const float*)d_in[4];
  float* out = (float*)d_out;
  char* ws = (char*)d_ws;

  // Workspace layout identical to rounds 4-7 (106,954,752 B, proven safe).
  const size_t need = 106954752;
  if (ws_size < need) return;

  unsigned short* Eh  = (unsigned short*)(ws);
  unsigned short* El  = (unsigned short*)(ws + 8388608);
  unsigned short* QMh = (unsigned short*)(ws + 16777216);
  unsigned short* QMl = (unsigned short*)(ws + 25165824);
  unsigned short* Vt  = QMh;  // alias, live only after scores
  unsigned short* MtH = (unsigned short*)(ws + 33554432);
  unsigned short* MtL = (unsigned short*)(ws + 35651584);
  unsigned short* Wvt = (unsigned short*)(ws + 37748736);
  float* scores       = (float*)(ws + 39845888);
  unsigned short* WqH = (unsigned short*)(ws + 39845888);
  unsigned short* WqL = (unsigned short*)(ws + 39845888 + 2097152);
  unsigned short* WkH = (unsigned short*)(ws + 39845888 + 4194304);
  unsigned short* WkL = (unsigned short*)(ws + 39845888 + 6291456);

  // ---- once: split weights, transpose Wv, precompute Mt = Wq*Wk^T ---------
  split32<<<1024, 256, 0, stream>>>(wq, WqH, WqL);
  split32<<<1024, 256, 0, stream>>>(wk, WkH, WkL);
  prep_wv<<<dim3(32, 32), dim3(32, 8), 0, stream>>>(wv, Wvt);
  gemm_bt<1, 0><<<dim3(8, 8), 256, 0, stream>>>(
      WkH, WkL, 1024, WqH, WqL, 1024, (void*)MtH, 1024, MtL, nullptr, 0.f, 32);

  for (int b = 0; b < 2; ++b) {
    const float* embb = emb + (size_t)b * 4096 * 1024;
    float* outb = out + (size_t)b * 4096 * 1024;

    // 1) split embeddings into bf16 hi/lo
    split32<<<4096, 256, 0, stream>>>(embb, Eh, El);
    // 2) QM = E*Mt^T (SPLIT, 128^2 engine), hi/lo store
    gemm_bt<1, 0><<<dim3(32, 8), 256, 0, stream>>>(
        Eh, El, 1024, MtH, MtL, 1024, (void*)QMh, 1024, QMl, nullptr, 0.f, 32);
    // 3) scores = (QM * E^T)/32 + mask_filled^T  (NEW 256^2 8-wave engine)
    gemm8s<<<dim3(16, 16), 512, 0, stream>>>(
        QMh, QMl, 1024, Eh, El, 1024, scores, 4096, mask, 0.03125f, 32);
    // 4) Vt = Wvt * E^T (plain bf16; overwrites dead QMh region)
    gemm_bt<0, 2><<<dim3(8, 32), 256, 0, stream>>>(
        Wvt, nullptr, 1024, Eh, nullptr, 1024, (void*)Vt, 4096, nullptr, nullptr, 0.f, 32);
    // 5) row softmax -> P bf16, in place (row stride 8192 ushorts)
    softmax_rows<<<4096, 256, 0, stream>>>(scores);
    // 6) out = P @ V (plain, 128^2 engine), fp32 store
    gemm_bt<0, 3><<<dim3(32, 8), 256, 0, stream>>>(
        (unsigned short*)scores, nullptr, 8192, Vt, nullptr, 4096,
        (void*)outb, 1024, nullptr, nullptr, 0.f, 128);
  }
}